// Round 10
// baseline (197.770 us; speedup 1.0000x reference)
//
#include <hip/hip_runtime.h>
#include <math.h>

#define LRELU(v) ((v) > 0.f ? (v) : 0.2f * (v))

// ===========================================================================
// R10 = R9 pipeline EXACTLY, with k3 launched 4x (3 extra, idempotent) as a
// timing probe: delta(total) / 3 = k3_dur + node_gap. R9 baseline 143.3 us.
// NO cross-workgroup sync of any kind (R7 CG grid.sync: 330us/sync; R8 spin
// barrier: ~80us idle; R8 fence+counter tail: ~35us regression). Kernel
// boundaries are the only affordable grid barrier on MI355X.
// ===========================================================================

// ---------------------------------------------------------------------------
// K1: h1 = lrelu(x@W1+b1) [1024,256]; h2 = h1@W2+b2 [1024,128]; BN stats.
// 512 blocks x 256 threads, 2 rows/block.
// ---------------------------------------------------------------------------
__global__ __launch_bounds__(256) void k1_mlp12(
    const float* __restrict__ x,
    const float* __restrict__ W1, const float* __restrict__ b1,
    const float* __restrict__ W2, const float* __restrict__ b2,
    float* __restrict__ h2g, float* __restrict__ stats)
{
    __shared__ float xs[256];
    __shared__ float h1s[512];
    __shared__ float ssum[256];
    __shared__ float ssq[256];
    const int t = threadIdx.x;
    const int r0 = blockIdx.x * 2;

    xs[t] = x[r0 * 128 + t];                    // 2 rows of x, coalesced
    __syncthreads();
    {
        float a0 = b1[t], a1 = a0;
        for (int k = 0; k < 128; ++k) {
            float w = W1[k * 256 + t];          // coalesced, feeds both rows
            a0 += xs[k] * w;
            a1 += xs[128 + k] * w;
        }
        h1s[t] = LRELU(a0);
        h1s[256 + t] = LRELU(a1);
    }
    __syncthreads();
    {
        const int c = t & 127;
        const int rr = t >> 7;
        float a = b2[c];
        for (int k = 0; k < 256; ++k)
            a += h1s[rr * 256 + k] * W2[k * 128 + c];
        h2g[(r0 + rr) * 128 + c] = a;
        ssum[t] = a;                            // t == rr*128 + c
        ssq[t] = a * a;
    }
    __syncthreads();
    if (t < 128)      atomicAdd(stats + t, ssum[t] + ssum[128 + t]);
    else { int c = t - 128; atomicAdd(stats + 128 + c, ssq[c] + ssq[128 + c]); }
}

// ---------------------------------------------------------------------------
// K2: BN+lrelu -> h3 -> attn(seq=1) -> h4 -> Mt = (h4@T2)^T.
// 512 blocks x 256 threads, 2 rows/block. Mt[260][1024] col-major,
// cols 250..259 zeroed so K3's ct=12 wave reads valid zeros.
// ---------------------------------------------------------------------------
__global__ __launch_bounds__(256) void k2_bn_attn_m(
    const float* __restrict__ h2g, const float* __restrict__ stats,
    const float* __restrict__ gamma, const float* __restrict__ beta,
    const float* __restrict__ W3, const float* __restrict__ b3,
    const float* __restrict__ Wv, const float* __restrict__ bv,
    const float* __restrict__ Wo, const float* __restrict__ bo,
    const float* __restrict__ T2,
    float* __restrict__ h4g, float* __restrict__ Mt)
{
    __shared__ float a[256];
    __shared__ float h3s[128];
    __shared__ float vss[128];
    __shared__ float h4s[128];
    const int t = threadIdx.x;
    const int r0 = blockIdx.x * 2;
    {
        const int c = t & 127;
        float s = stats[c], ss = stats[128 + c];
        float mean = s * (1.f / 1024.f);
        float var = ss * (1.f / 1024.f) - mean * mean;
        float rstd = rsqrtf(var + 1e-5f);
        float v = (h2g[r0 * 128 + t] - mean) * rstd * gamma[c] + beta[c];
        a[t] = LRELU(v);
    }
    __syncthreads();
    const int row = t >> 6, col = t & 63;
    if (t < 128) {
        float acc = b3[col];
        for (int k = 0; k < 128; ++k) acc += a[row * 128 + k] * W3[k * 64 + col];
        h3s[row * 64 + col] = LRELU(acc);
    }
    __syncthreads();
    if (t < 128) {
        float acc = bv[col];
        for (int k = 0; k < 64; ++k) acc += h3s[row * 64 + k] * Wv[k * 64 + col];
        vss[row * 64 + col] = acc;
    }
    __syncthreads();
    if (t < 128) {
        float acc = bo[col];
        for (int k = 0; k < 64; ++k) acc += vss[row * 64 + k] * Wo[k * 64 + col];
        float h4 = h3s[row * 64 + col] + acc;
        h4s[row * 64 + col] = h4;
        h4g[(r0 + row) * 64 + col] = h4;
    }
    __syncthreads();
    if (t < 250) {
        float m0 = 0.f, m1 = 0.f;
        for (int k = 0; k < 64; ++k) {
            float w = T2[k * 250 + t];          // coalesced, feeds both rows
            m0 += h4s[k] * w;
            m1 += h4s[64 + k] * w;
        }
        Mt[(size_t)t * 1024 + r0]     = m0;
        Mt[(size_t)t * 1024 + r0 + 1] = m1;
    } else {
        Mt[(size_t)t * 1024 + r0]     = 0.f;
        Mt[(size_t)t * 1024 + r0 + 1] = 0.f;
    }
    if (t < 4) {
        Mt[(size_t)(256 + t) * 1024 + r0]     = 0.f;
        Mt[(size_t)(256 + t) * 1024 + r0 + 1] = 0.f;
    }
}

// ---------------------------------------------------------------------------
// K3: all-pairs L1 + exp. One (j,c) per thread.
// Grid = 16 jt x 13 ct x 8 ic = 1664 blocks (~26 waves/CU).
// Idempotent: plain overwrite of opart -> safe to launch multiple times.
// ---------------------------------------------------------------------------
__global__ __launch_bounds__(256) void k3_pairs(
    const float* __restrict__ Mt, float* __restrict__ opart)
{
    __shared__ float mi[2560];                  // [20 cols][128 i]
    const int t = threadIdx.x;
    const int b = blockIdx.x;
    const int jt = b / 104;
    const int rem = b - jt * 104;
    const int ct = rem >> 3;
    const int ic = rem & 7;
    const int jl = t & 63, cl = t >> 6;
    const int j = jt * 64 + jl;
    const int c = ct * 4 + cl;                  // 0..51 (50,51 read zero pad)
    const int i0 = ic * 128;

    for (int qq = 0; qq < 10; ++qq) {
        int idx = qq * 256 + t;
        int cc = idx >> 7, il = idx & 127;
        mi[idx] = Mt[(size_t)(ct * 20 + cc) * 1024 + i0 + il];
    }
    float mj0 = Mt[(size_t)(c * 5 + 0) * 1024 + j];
    float mj1 = Mt[(size_t)(c * 5 + 1) * 1024 + j];
    float mj2 = Mt[(size_t)(c * 5 + 2) * 1024 + j];
    float mj3 = Mt[(size_t)(c * 5 + 3) * 1024 + j];
    float mj4 = Mt[(size_t)(c * 5 + 4) * 1024 + j];
    __syncthreads();

    const float4* m0 = (const float4*)(mi + (cl * 5 + 0) * 128);
    const float4* m1 = (const float4*)(mi + (cl * 5 + 1) * 128);
    const float4* m2 = (const float4*)(mi + (cl * 5 + 2) * 128);
    const float4* m3 = (const float4*)(mi + (cl * 5 + 3) * 128);
    const float4* m4 = (const float4*)(mi + (cl * 5 + 4) * 128);

    float acc0 = 0.f, acc1 = 0.f, acc2 = 0.f, acc3 = 0.f;
    for (int q = 0; q < 32; ++q) {
        float4 v0 = m0[q], v1 = m1[q], v2 = m2[q], v3 = m3[q], v4 = m4[q];
        float d0 = fabsf(v0.x - mj0) + fabsf(v1.x - mj1) + fabsf(v2.x - mj2)
                 + fabsf(v3.x - mj3) + fabsf(v4.x - mj4);
        float d1 = fabsf(v0.y - mj0) + fabsf(v1.y - mj1) + fabsf(v2.y - mj2)
                 + fabsf(v3.y - mj3) + fabsf(v4.y - mj4);
        float d2 = fabsf(v0.z - mj0) + fabsf(v1.z - mj1) + fabsf(v2.z - mj2)
                 + fabsf(v3.z - mj3) + fabsf(v4.z - mj4);
        float d3 = fabsf(v0.w - mj0) + fabsf(v1.w - mj1) + fabsf(v2.w - mj2)
                 + fabsf(v3.w - mj3) + fabsf(v4.w - mj4);
        acc0 += __expf(-d0);
        acc1 += __expf(-d1);
        acc2 += __expf(-d2);
        acc3 += __expf(-d3);
    }
    opart[(size_t)(ic * 1024 + j) * 52 + c] = (acc0 + acc1) + (acc2 + acc3);
}

// ---------------------------------------------------------------------------
// K4: reduce 8 partials, subtract self-term, dot feat=[h4,o] with Ws, +bs.
// ---------------------------------------------------------------------------
__global__ __launch_bounds__(64) void k4_score(
    const float* __restrict__ h4g, const float* __restrict__ opart,
    const float* __restrict__ Ws, const float* __restrict__ bs,
    float* __restrict__ out)
{
    const int j = blockIdx.x, t = threadIdx.x;
    float contrib = h4g[j * 64 + t] * Ws[t];
    if (t < 50) {
        float s = 0.f;
        for (int ic = 0; ic < 8; ++ic)
            s += opart[(size_t)(ic * 1024 + j) * 52 + t];
        contrib += (s - 1.0f) * Ws[64 + t];     // -1 removes self term exp(0)
    }
    for (int off = 32; off > 0; off >>= 1)
        contrib += __shfl_down(contrib, off, 64);
    if (t == 0) out[j] = contrib + bs[0];
}

// ---------------------------------------------------------------------------
// ws layout (float offsets):
//   h2    @ 0       (131072)
//   stats @ 131072  (256)
//   h4    @ 131328  (65536)
//   Mt    @ 196864  (260*1024 = 266240, col-major transpose of M)
//   opart @ 463104  (8*1024*52 = 425984)
// ---------------------------------------------------------------------------
extern "C" void kernel_launch(void* const* d_in, const int* in_sizes, int n_in,
                              void* d_out, int out_size, void* d_ws, size_t ws_size,
                              hipStream_t stream)
{
    const float* x     = (const float*)d_in[0];
    const float* W1    = (const float*)d_in[1];
    const float* b1    = (const float*)d_in[2];
    const float* W2    = (const float*)d_in[3];
    const float* b2    = (const float*)d_in[4];
    const float* gamma = (const float*)d_in[5];
    const float* beta  = (const float*)d_in[6];
    const float* W3    = (const float*)d_in[7];
    const float* b3    = (const float*)d_in[8];
    const float* Wv    = (const float*)d_in[9];
    const float* bv    = (const float*)d_in[10];
    const float* Wo    = (const float*)d_in[11];
    const float* bo    = (const float*)d_in[12];
    const float* T2    = (const float*)d_in[13];
    const float* Ws    = (const float*)d_in[14];
    const float* bs    = (const float*)d_in[15];

    float* ws    = (float*)d_ws;
    float* h2    = ws + 0;
    float* stats = ws + 131072;
    float* h4    = ws + 131328;
    float* Mt    = ws + 196864;
    float* opart = ws + 463104;
    float* out   = (float*)d_out;

    hipMemsetAsync(stats, 0, 256 * sizeof(float), stream);
    hipLaunchKernelGGL(k1_mlp12, dim3(512), dim3(256), 0, stream,
                       x, W1, b1, W2, b2, h2, stats);
    hipLaunchKernelGGL(k2_bn_attn_m, dim3(512), dim3(256), 0, stream,
                       h2, stats, gamma, beta, W3, b3, Wv, bv, Wo, bo, T2, h4, Mt);
    // --- k3 x4: 3 extra idempotent launches as a timing probe ---
    hipLaunchKernelGGL(k3_pairs, dim3(1664), dim3(256), 0, stream, Mt, opart);
    hipLaunchKernelGGL(k3_pairs, dim3(1664), dim3(256), 0, stream, Mt, opart);
    hipLaunchKernelGGL(k3_pairs, dim3(1664), dim3(256), 0, stream, Mt, opart);
    hipLaunchKernelGGL(k3_pairs, dim3(1664), dim3(256), 0, stream, Mt, opart);
    hipLaunchKernelGGL(k4_score, dim3(1024), dim3(64), 0, stream,
                       h4, opart, Ws, bs, out);
}

// Round 11
// 144.961 us; speedup vs baseline: 1.3643x; 1.3643x over previous
//
#include <hip/hip_runtime.h>
#include <math.h>

#define LRELU(v) ((v) > 0.f ? (v) : 0.2f * (v))

// ===========================================================================
// R11: R9 pipeline with k1/k2 widened to 512 threads/block (16 waves/CU,
// was 8) via k-split dots -- same weight traffic, 2x latency hiding.
// k2 pre-scales Mt by log2(e) so k3 uses exp2f (drops one v_mul/element).
// Measured landmarks: k3+gap = 18.2us (R10 probe); cross-workgroup sync
// banned (R7 CG 330us/sync, R8 spin ~80us, R8 fence tail +35us).
// ===========================================================================

// ---------------------------------------------------------------------------
// K1: h1 = lrelu(x@W1+b1); h2 = h1@W2+b2; BN stats. 512 blocks x 512 thr,
// 2 rows/block. h1: (col,row) full dots. h2: (c,rr,khalf) partials + combine.
// ---------------------------------------------------------------------------
__global__ __launch_bounds__(512) void k1_mlp12(
    const float* __restrict__ x,
    const float* __restrict__ W1, const float* __restrict__ b1,
    const float* __restrict__ W2, const float* __restrict__ b2,
    float* __restrict__ h2g, float* __restrict__ stats)
{
    __shared__ float xs[256];
    __shared__ float h1s[512];
    __shared__ float hp[512];
    __shared__ float ssum[256];
    __shared__ float ssq[256];
    const int t = threadIdx.x;
    const int r0 = blockIdx.x * 2;

    if (t < 256) xs[t] = x[r0 * 128 + t];
    __syncthreads();
    {   // h1: thread (col = t&255, row = t>>8), full 128-dot
        const int col = t & 255, row = t >> 8;
        const float* xr = xs + row * 128;
        float a0 = b1[col];
        for (int k = 0; k < 128; ++k)
            a0 += xr[k] * W1[k * 256 + col];          // coalesced
        h1s[row * 256 + col] = LRELU(a0);
    }
    __syncthreads();
    {   // h2 partials: thread (c = t&127, rr = (t>>7)&1, kh = t>>8), 128-dot
        const int c = t & 127, rr = (t >> 7) & 1, kh = t >> 8;
        const float* h1r = h1s + rr * 256 + kh * 128;
        const float* w2 = W2 + kh * 128 * 128;
        float p = 0.f;
        for (int k = 0; k < 128; ++k)
            p += h1r[k] * w2[k * 128 + c];            // coalesced
        hp[t] = p;                                    // t = kh*256 + rr*128 + c
    }
    __syncthreads();
    if (t < 256) {
        const int c = t & 127, rr = t >> 7;
        float v = hp[rr * 128 + c] + hp[256 + rr * 128 + c] + b2[c];
        h2g[(r0 + rr) * 128 + c] = v;
        ssum[t] = v;                                  // t = rr*128 + c
        ssq[t] = v * v;
    }
    __syncthreads();
    if (t < 128)      atomicAdd(stats + t, ssum[t] + ssum[128 + t]);
    else if (t < 256) { int c = t - 128; atomicAdd(stats + 128 + c, ssq[c] + ssq[128 + c]); }
}

// ---------------------------------------------------------------------------
// K2: BN+lrelu -> h3 -> attn(seq=1) -> h4 -> Mt = (h4@T2)^T * log2(e).
// 512 blocks x 512 threads, 2 rows/block; 4-way k-split partial dots.
// Mt[260][1024] col-major, cols 250..259 zeroed (k3 ct=12 reads zeros).
// ---------------------------------------------------------------------------
__global__ __launch_bounds__(512) void k2_bn_attn_m(
    const float* __restrict__ h2g, const float* __restrict__ stats,
    const float* __restrict__ gamma, const float* __restrict__ beta,
    const float* __restrict__ W3, const float* __restrict__ b3,
    const float* __restrict__ Wv, const float* __restrict__ bv,
    const float* __restrict__ Wo, const float* __restrict__ bo,
    const float* __restrict__ T2,
    float* __restrict__ h4g, float* __restrict__ Mt)
{
    __shared__ float a[256];
    __shared__ float hp[512];
    __shared__ float h3s[128];
    __shared__ float vss[128];
    __shared__ float h4s[128];
    const int t = threadIdx.x;
    const int r0 = blockIdx.x * 2;

    if (t < 256) {
        const int c = t & 127;
        float s = stats[c], ss = stats[128 + c];
        float mean = s * (1.f / 1024.f);
        float var = ss * (1.f / 1024.f) - mean * mean;
        float rstd = rsqrtf(var + 1e-5f);
        float v = (h2g[r0 * 128 + t] - mean) * rstd * gamma[c] + beta[c];
        a[t] = LRELU(v);
    }
    __syncthreads();
    const int col = t & 63, row = (t >> 6) & 1, kq = t >> 7;   // kq 0..3
    {   // h3 partials: 32 k each
        const float* ar = a + row * 128 + kq * 32;
        float p = 0.f;
        for (int k = 0; k < 32; ++k)
            p += ar[k] * W3[(kq * 32 + k) * 64 + col];
        hp[t] = p;                                    // t = kq*128 + row*64 + col
    }
    __syncthreads();
    if (t < 128) {
        const int cc = t & 63, rr = t >> 6, o = rr * 64 + cc;
        h3s[o] = LRELU(hp[o] + hp[128 + o] + hp[256 + o] + hp[384 + o] + b3[cc]);
    }
    __syncthreads();
    {   // v partials: 16 k each
        const float* hr = h3s + row * 64 + kq * 16;
        float p = 0.f;
        for (int k = 0; k < 16; ++k)
            p += hr[k] * Wv[(kq * 16 + k) * 64 + col];
        hp[t] = p;
    }
    __syncthreads();
    if (t < 128) {
        const int cc = t & 63, rr = t >> 6, o = rr * 64 + cc;
        vss[o] = hp[o] + hp[128 + o] + hp[256 + o] + hp[384 + o] + bv[cc];
    }
    __syncthreads();
    {   // h4 partials: 16 k each over vss
        const float* vr = vss + row * 64 + kq * 16;
        float p = 0.f;
        for (int k = 0; k < 16; ++k)
            p += vr[k] * Wo[(kq * 16 + k) * 64 + col];
        hp[t] = p;
    }
    __syncthreads();
    if (t < 128) {
        const int cc = t & 63, rr = t >> 6, o = rr * 64 + cc;
        float h4 = h3s[o] + hp[o] + hp[128 + o] + hp[256 + o] + hp[384 + o] + bo[cc];
        h4s[o] = h4;
        h4g[(r0 + rr) * 64 + cc] = h4;
    }
    __syncthreads();
    // Mt = (h4 @ T2)^T * log2(e)  (|a-b|*s == |as-bs| for s>0; k3 uses exp2f)
    const float LOG2E = 1.44269504088896340736f;
    if (t < 500) {
        const int rr = t / 250, c = t - rr * 250;
        float m = 0.f;
        for (int k = 0; k < 64; ++k)
            m += h4s[rr * 64 + k] * T2[k * 250 + c];  // coalesced across c
        Mt[(size_t)c * 1024 + r0 + rr] = m * LOG2E;
    } else if (t < 520) {
        const int idx = t - 500;
        const int c = 250 + (idx >> 1), rr = idx & 1;
        Mt[(size_t)c * 1024 + r0 + rr] = 0.f;
    }
}

// ---------------------------------------------------------------------------
// K3: all-pairs L1 + exp2 (Mt prescaled). One (j,c) per thread.
// Grid = 16 jt x 13 ct x 8 ic = 1664 blocks (~26 waves/CU). R10 probe:
// k3+gap = 18.2us. LDS compute reads are wave-uniform broadcasts.
// ---------------------------------------------------------------------------
__global__ __launch_bounds__(256) void k3_pairs(
    const float* __restrict__ Mt, float* __restrict__ opart)
{
    __shared__ float mi[2560];                  // [20 cols][128 i]
    const int t = threadIdx.x;
    const int b = blockIdx.x;
    const int jt = b / 104;
    const int rem = b - jt * 104;
    const int ct = rem >> 3;
    const int ic = rem & 7;
    const int jl = t & 63, cl = t >> 6;
    const int j = jt * 64 + jl;
    const int c = ct * 4 + cl;                  // 0..51 (50,51 read zero pad)
    const int i0 = ic * 128;

    for (int qq = 0; qq < 10; ++qq) {
        int idx = qq * 256 + t;
        int cc = idx >> 7, il = idx & 127;
        mi[idx] = Mt[(size_t)(ct * 20 + cc) * 1024 + i0 + il];
    }
    float mj0 = Mt[(size_t)(c * 5 + 0) * 1024 + j];
    float mj1 = Mt[(size_t)(c * 5 + 1) * 1024 + j];
    float mj2 = Mt[(size_t)(c * 5 + 2) * 1024 + j];
    float mj3 = Mt[(size_t)(c * 5 + 3) * 1024 + j];
    float mj4 = Mt[(size_t)(c * 5 + 4) * 1024 + j];
    __syncthreads();

    const float4* m0 = (const float4*)(mi + (cl * 5 + 0) * 128);
    const float4* m1 = (const float4*)(mi + (cl * 5 + 1) * 128);
    const float4* m2 = (const float4*)(mi + (cl * 5 + 2) * 128);
    const float4* m3 = (const float4*)(mi + (cl * 5 + 3) * 128);
    const float4* m4 = (const float4*)(mi + (cl * 5 + 4) * 128);

    float acc0 = 0.f, acc1 = 0.f, acc2 = 0.f, acc3 = 0.f;
    for (int q = 0; q < 32; ++q) {
        float4 v0 = m0[q], v1 = m1[q], v2 = m2[q], v3 = m3[q], v4 = m4[q];
        float d0 = fabsf(v0.x - mj0) + fabsf(v1.x - mj1) + fabsf(v2.x - mj2)
                 + fabsf(v3.x - mj3) + fabsf(v4.x - mj4);
        float d1 = fabsf(v0.y - mj0) + fabsf(v1.y - mj1) + fabsf(v2.y - mj2)
                 + fabsf(v3.y - mj3) + fabsf(v4.y - mj4);
        float d2 = fabsf(v0.z - mj0) + fabsf(v1.z - mj1) + fabsf(v2.z - mj2)
                 + fabsf(v3.z - mj3) + fabsf(v4.z - mj4);
        float d3 = fabsf(v0.w - mj0) + fabsf(v1.w - mj1) + fabsf(v2.w - mj2)
                 + fabsf(v3.w - mj3) + fabsf(v4.w - mj4);
        acc0 += exp2f(-d0);                     // v_exp_f32 directly (prescaled)
        acc1 += exp2f(-d1);
        acc2 += exp2f(-d2);
        acc3 += exp2f(-d3);
    }
    opart[(size_t)(ic * 1024 + j) * 52 + c] = (acc0 + acc1) + (acc2 + acc3);
}

// ---------------------------------------------------------------------------
// K4: reduce 8 partials, subtract self-term, dot feat=[h4,o] with Ws, +bs.
// ---------------------------------------------------------------------------
__global__ __launch_bounds__(64) void k4_score(
    const float* __restrict__ h4g, const float* __restrict__ opart,
    const float* __restrict__ Ws, const float* __restrict__ bs,
    float* __restrict__ out)
{
    const int j = blockIdx.x, t = threadIdx.x;
    float contrib = h4g[j * 64 + t] * Ws[t];
    if (t < 50) {
        float s = 0.f;
        for (int ic = 0; ic < 8; ++ic)
            s += opart[(size_t)(ic * 1024 + j) * 52 + t];
        contrib += (s - 1.0f) * Ws[64 + t];     // -1 removes self term exp(0)
    }
    for (int off = 32; off > 0; off >>= 1)
        contrib += __shfl_down(contrib, off, 64);
    if (t == 0) out[j] = contrib + bs[0];
}

// ---------------------------------------------------------------------------
// ws layout (float offsets):
//   h2    @ 0       (131072)
//   stats @ 131072  (256)
//   h4    @ 131328  (65536)
//   Mt    @ 196864  (260*1024 = 266240, col-major, pre-scaled by log2e)
//   opart @ 463104  (8*1024*52 = 425984)
// ---------------------------------------------------------------------------
extern "C" void kernel_launch(void* const* d_in, const int* in_sizes, int n_in,
                              void* d_out, int out_size, void* d_ws, size_t ws_size,
                              hipStream_t stream)
{
    const float* x     = (const float*)d_in[0];
    const float* W1    = (const float*)d_in[1];
    const float* b1    = (const float*)d_in[2];
    const float* W2    = (const float*)d_in[3];
    const float* b2    = (const float*)d_in[4];
    const float* gamma = (const float*)d_in[5];
    const float* beta  = (const float*)d_in[6];
    const float* W3    = (const float*)d_in[7];
    const float* b3    = (const float*)d_in[8];
    const float* Wv    = (const float*)d_in[9];
    const float* bv    = (const float*)d_in[10];
    const float* Wo    = (const float*)d_in[11];
    const float* bo    = (const float*)d_in[12];
    const float* T2    = (const float*)d_in[13];
    const float* Ws    = (const float*)d_in[14];
    const float* bs    = (const float*)d_in[15];

    float* ws    = (float*)d_ws;
    float* h2    = ws + 0;
    float* stats = ws + 131072;
    float* h4    = ws + 131328;
    float* Mt    = ws + 196864;
    float* opart = ws + 463104;
    float* out   = (float*)d_out;

    hipMemsetAsync(stats, 0, 256 * sizeof(float), stream);
    hipLaunchKernelGGL(k1_mlp12, dim3(512), dim3(512), 0, stream,
                       x, W1, b1, W2, b2, h2, stats);
    hipLaunchKernelGGL(k2_bn_attn_m, dim3(512), dim3(512), 0, stream,
                       h2, stats, gamma, beta, W3, b3, Wv, bv, Wo, bo, T2, h4, Mt);
    hipLaunchKernelGGL(k3_pairs, dim3(1664), dim3(256), 0, stream, Mt, opart);
    hipLaunchKernelGGL(k4_score, dim3(1024), dim3(64), 0, stream,
                       h4, opart, Ws, bs, out);
}